// Round 3
// baseline (483.818 us; speedup 1.0000x reference)
//
#include <hip/hip_runtime.h>
#include <hip/hip_bf16.h>

#define N_ROWS 8192
#define DIM 512
#define SCALE 2.659f
#define MAXLOGIT 2.659f
#define NCHUNK 8
#define CHUNK 1024
#define BM 128
#define BN 128
#define LOG2E 1.44269504f

typedef __attribute__((ext_vector_type(8))) short short8;
typedef __attribute__((ext_vector_type(4))) float f32x4;

__device__ __forceinline__ unsigned short f2bf(float f) {
    unsigned int u = __float_as_uint(f);
    u += 0x7fffu + ((u >> 16) & 1u);
    return (unsigned short)(u >> 16);
}

// ---------------------------------------------------------------- normalize
__global__ __launch_bounds__(256) void norm_cast_kernel(
    const float* __restrict__ text, const float* __restrict__ image,
    unsigned short* __restrict__ imgn, unsigned short* __restrict__ txtn)
{
    int row  = blockIdx.x * 4 + (threadIdx.x >> 6);
    int lane = threadIdx.x & 63;
    const float* src;
    unsigned short* dst;
    if (row < N_ROWS) { src = image + (size_t)row * DIM; dst = imgn + (size_t)row * DIM; }
    else { int r = row - N_ROWS; src = text + (size_t)r * DIM; dst = txtn + (size_t)r * DIM; }
    const float4* s4 = (const float4*)src + lane * 2;
    float4 a = s4[0], b = s4[1];
    float ss = a.x*a.x + a.y*a.y + a.z*a.z + a.w*a.w
             + b.x*b.x + b.y*b.y + b.z*b.z + b.w*b.w;
    #pragma unroll
    for (int m = 1; m < 64; m <<= 1) ss += __shfl_xor(ss, m, 64);
    float sc = 1.0f / fmaxf(sqrtf(ss), 1e-12f);
    uint4 o;
    o.x = (unsigned)f2bf(a.x*sc) | ((unsigned)f2bf(a.y*sc) << 16);
    o.y = (unsigned)f2bf(a.z*sc) | ((unsigned)f2bf(a.w*sc) << 16);
    o.z = (unsigned)f2bf(b.x*sc) | ((unsigned)f2bf(b.y*sc) << 16);
    o.w = (unsigned)f2bf(b.z*sc) | ((unsigned)f2bf(b.w*sc) << 16);
    *((uint4*)dst + lane) = o;
}

// ---------------------------------------------------------------- histogram
__global__ __launch_bounds__(256) void hist_kernel(
    const int* __restrict__ labels, int* __restrict__ hist_g)
{
    __shared__ int hist[128];
    int tid = threadIdx.x;
    if (tid < 128) hist[tid] = 0;
    __syncthreads();
    for (int i = tid; i < N_ROWS; i += 256) {
        int lb = labels[i];
        if (lb >= 0) atomicAdd(&hist[lb], 1);
    }
    __syncthreads();
    if (tid < 128) hist_g[tid] = hist[tid];
}

// ---------------------------------------------------------------- fused GEMM
#define ASYNC16(gp, lp) \
  __builtin_amdgcn_global_load_lds((const __attribute__((address_space(1))) void*)(gp), \
                                   (__attribute__((address_space(3))) void*)(lp), 16, 0, 0)

__global__ __launch_bounds__(256, 4) void gemm_fused_kernel(
    const unsigned short* __restrict__ imgn, const unsigned short* __restrict__ txtn,
    const int* __restrict__ labels, float2* __restrict__ part)
{
    __shared__ unsigned short Ald[BM * 32];
    __shared__ unsigned short Bld[BN * 32];
    __shared__ int labL[CHUNK];
    __shared__ float red[2][BM][2];

    int bid    = blockIdx.x;
    int dir    = bid >> 9;       // 0: rows=img, 1: rows=txt
    int rem    = bid & 511;
    int rowblk = rem & 63;
    int chunk  = rem >> 6;
    const unsigned short* A = dir ? txtn : imgn;
    const unsigned short* B = dir ? imgn : txtn;
    int rowBase  = rowblk * BM;
    int colBase0 = chunk * CHUNK;

    int tid  = threadIdx.x;
    int lane = tid & 63;
    int w    = tid >> 6;
    int wr   = w >> 1, wc = w & 1;
    int q    = lane >> 4;
    int lm   = lane & 15;

    // stage chunk labels (with diagonal-sentinel transform) into LDS
    #pragma unroll
    for (int i = 0; i < CHUNK / 256; ++i) {
        int jl = i * 256 + tid;
        int jg = colBase0 + jl;
        int lb = labels[jg];
        labL[jl] = lb < 0 ? (-jg - 2) : lb;
    }

    // this lane's 16 accumulator rows: rowQ + mi*16 + r
    int rowQ = rowBase + wr * 64 + q * 4;
    int labRm[16];
    #pragma unroll
    for (int mi = 0; mi < 4; ++mi)
      #pragma unroll
      for (int r = 0; r < 4; ++r) {
        int gr = rowQ + mi*16 + r;
        int lb = labels[gr];
        labRm[mi*4 + r] = lb < 0 ? (-gr - 2) : lb;
      }

    float s_acc[16], d_acc[16];
    #pragma unroll
    for (int i = 0; i < 16; ++i) { s_acc[i] = 0.f; d_acc[i] = 0.f; }

    int srow  = lane >> 2;        // staging: row within 16-row group
    int spart = (lane & 3) * 8;   // staging: k offset (elems)

    const float C1 = SCALE * LOG2E;
    const float C2 = -MAXLOGIT * LOG2E;

    for (int tile = 0; tile < CHUNK / BN; ++tile) {
        int colBase = colBase0 + tile * BN;
        f32x4 acc[4][4];
        #pragma unroll
        for (int mi = 0; mi < 4; ++mi)
          #pragma unroll
          for (int ni = 0; ni < 4; ++ni)
            acc[mi][ni] = (f32x4){0.f, 0.f, 0.f, 0.f};

        for (int kt = 0; kt < DIM / 32; ++kt) {
            int k0 = kt * 32;
            __syncthreads();   // all waves done reading LDS before re-stage
            #pragma unroll
            for (int i = 0; i < 2; ++i) {
                int rlocal = i*64 + w*16 + srow;
                ASYNC16(A + (size_t)(rowBase + rlocal) * DIM + k0 + spart,
                        Ald + (i*64 + w*16) * 32);
                ASYNC16(B + (size_t)(colBase + rlocal) * DIM + k0 + spart,
                        Bld + (i*64 + w*16) * 32);
            }
            __syncthreads();   // drains vmcnt(0): staging complete

            short8 af[4], bf[4];
            #pragma unroll
            for (int mi = 0; mi < 4; ++mi)
                af[mi] = *(const short8*)(Ald + (wr*64 + mi*16 + lm)*32 + q*8);
            #pragma unroll
            for (int ni = 0; ni < 4; ++ni)
                bf[ni] = *(const short8*)(Bld + (wc*64 + ni*16 + lm)*32 + q*8);
            #pragma unroll
            for (int mi = 0; mi < 4; ++mi)
              #pragma unroll
              for (int ni = 0; ni < 4; ++ni)
                acc[mi][ni] = __builtin_amdgcn_mfma_f32_16x16x32_bf16(
                                  af[mi], bf[ni], acc[mi][ni], 0, 0, 0);
        }

        // epilogue: fixed-max (2.659) accumulation — pure commutative sums
        #pragma unroll
        for (int ni = 0; ni < 4; ++ni) {
            int jl   = tile * BN + wc*64 + ni*16 + lm;
            int labj = labL[jl];
            #pragma unroll
            for (int mi = 0; mi < 4; ++mi) {
              #pragma unroll
              for (int r = 0; r < 4; ++r) {
                int   idx = mi*4 + r;
                float a   = acc[mi][ni][r];
                s_acc[idx] += __builtin_amdgcn_exp2f(__fmaf_rn(a, C1, C2));
                d_acc[idx] += (labj == labRm[idx]) ? a : 0.0f;
              }
            }
        }
    }

    // reduce across the 16 column-lanes (low 4 lane bits)
    #pragma unroll
    for (int idx = 0; idx < 16; ++idx) {
        float s = s_acc[idx], d = d_acc[idx];
        #pragma unroll
        for (int m = 1; m < 16; m <<= 1) {
            s += __shfl_xor(s, m, 64);
            d += __shfl_xor(d, m, 64);
        }
        s_acc[idx] = s; d_acc[idx] = d;
    }
    if (lm == 0) {
        #pragma unroll
        for (int idx = 0; idx < 16; ++idx) {
            int rl = wr*64 + (idx>>2)*16 + q*4 + (idx&3);
            red[wc][rl][0] = s_acc[idx];
            red[wc][rl][1] = d_acc[idx] * SCALE;
        }
    }
    __syncthreads();
    if (tid < BM) {
        float s = red[0][tid][0] + red[1][tid][0];
        float d = red[0][tid][1] + red[1][tid][1];
        part[(size_t)(dir * NCHUNK + chunk) * N_ROWS + rowBase + tid] = make_float2(s, d);
    }
}

// ---------------------------------------------------------------- loss stage 1
__global__ __launch_bounds__(256) void loss_stage1_kernel(
    const int* __restrict__ labels, const float2* __restrict__ part,
    const int* __restrict__ hist, float* __restrict__ partial)
{
    __shared__ float wsum[4];
    int tid  = threadIdx.x;
    int task = blockIdx.x * 256 + tid;
    int dir  = task >> 13;
    int i    = task & (N_ROWS - 1);
    float s = 0.f, d = 0.f;
    #pragma unroll
    for (int c = 0; c < NCHUNK; ++c) {
        float2 p = part[(size_t)(dir * NCHUNK + c) * N_ROWS + i];
        s += p.x; d += p.y;
    }
    int lb = labels[i];
    float sT = (lb < 0) ? 1.0f : (float)hist[lb];
    float local = (MAXLOGIT + __logf(s)) - d / sT;
    #pragma unroll
    for (int m = 1; m < 64; m <<= 1) local += __shfl_xor(local, m, 64);
    if ((tid & 63) == 0) wsum[tid >> 6] = local;
    __syncthreads();
    if (tid == 0)
        partial[blockIdx.x] = wsum[0] + wsum[1] + wsum[2] + wsum[3];
}

// ---------------------------------------------------------------- loss stage 2
__global__ __launch_bounds__(64) void loss_stage2_kernel(
    const float* __restrict__ partial, float* __restrict__ out)
{
    int lane = threadIdx.x;
    float v = partial[lane];
    #pragma unroll
    for (int m = 1; m < 64; m <<= 1) v += __shfl_xor(v, m, 64);
    if (lane == 0) out[0] = v * (1.0f / (2 * N_ROWS));
}

// ---------------------------------------------------------------- launch
extern "C" void kernel_launch(void* const* d_in, const int* in_sizes, int n_in,
                              void* d_out, int out_size, void* d_ws, size_t ws_size,
                              hipStream_t stream)
{
    const float* text   = (const float*)d_in[0];
    const float* image  = (const float*)d_in[1];
    const int*   labels = (const int*)d_in[2];

    unsigned short* imgn = (unsigned short*)d_ws;
    unsigned short* txtn = imgn + (size_t)N_ROWS * DIM;
    char* base = (char*)d_ws + 2 * (size_t)N_ROWS * DIM * sizeof(unsigned short);
    float2* part   = (float2*)base;                                    // 1 MB
    int*    hist   = (int*)(base + 2 * NCHUNK * (size_t)N_ROWS * 8);   // 512 B
    float*  partial = (float*)(hist + 128);                            // 256 B
    float*  out    = (float*)d_out;

    hipLaunchKernelGGL(norm_cast_kernel, dim3(2 * N_ROWS / 4), dim3(256), 0, stream,
                       text, image, imgn, txtn);
    hipLaunchKernelGGL(hist_kernel, dim3(1), dim3(256), 0, stream, labels, hist);
    hipLaunchKernelGGL(gemm_fused_kernel, dim3(2 * 64 * NCHUNK), dim3(256), 0, stream,
                       imgn, txtn, labels, part);
    hipLaunchKernelGGL(loss_stage1_kernel, dim3(2 * N_ROWS / 256), dim3(256), 0, stream,
                       labels, part, hist, partial);
    hipLaunchKernelGGL(loss_stage2_kernel, dim3(1), dim3(64), 0, stream, partial, out);
}

// Round 4
// 453.731 us; speedup vs baseline: 1.0663x; 1.0663x over previous
//
#include <hip/hip_runtime.h>
#include <hip/hip_bf16.h>

#define N_ROWS 8192
#define DIM 512
#define SCALE 2.659f
#define MAXLOGIT 2.659f
#define NCHUNK 16
#define CHUNK 512
#define BM 128
#define BN 128
#define NLAB 128
#define LOG2E 1.44269504f

typedef __attribute__((ext_vector_type(8))) short short8;
typedef __attribute__((ext_vector_type(4))) float f32x4;

__device__ __forceinline__ unsigned short f2bf(float f) {
    unsigned int u = __float_as_uint(f);
    u += 0x7fffu + ((u >> 16) & 1u);
    return (unsigned short)(u >> 16);
}
__device__ __forceinline__ float bflo(unsigned int u) { return __uint_as_float(u << 16); }
__device__ __forceinline__ float bfhi(unsigned int u) { return __uint_as_float(u & 0xffff0000u); }

// ---------------------------------------------------------------- normalize
__global__ __launch_bounds__(256) void norm_cast_kernel(
    const float* __restrict__ text, const float* __restrict__ image,
    unsigned short* __restrict__ imgn, unsigned short* __restrict__ txtn)
{
    int row  = blockIdx.x * 4 + (threadIdx.x >> 6);
    int lane = threadIdx.x & 63;
    const float* src;
    unsigned short* dst;
    if (row < N_ROWS) { src = image + (size_t)row * DIM; dst = imgn + (size_t)row * DIM; }
    else { int r = row - N_ROWS; src = text + (size_t)r * DIM; dst = txtn + (size_t)r * DIM; }
    const float4* s4 = (const float4*)src + lane * 2;
    float4 a = s4[0], b = s4[1];
    float ss = a.x*a.x + a.y*a.y + a.z*a.z + a.w*a.w
             + b.x*b.x + b.y*b.y + b.z*b.z + b.w*b.w;
    #pragma unroll
    for (int m = 1; m < 64; m <<= 1) ss += __shfl_xor(ss, m, 64);
    float sc = 1.0f / fmaxf(sqrtf(ss), 1e-12f);
    uint4 o;
    o.x = (unsigned)f2bf(a.x*sc) | ((unsigned)f2bf(a.y*sc) << 16);
    o.y = (unsigned)f2bf(a.z*sc) | ((unsigned)f2bf(a.w*sc) << 16);
    o.z = (unsigned)f2bf(b.x*sc) | ((unsigned)f2bf(b.y*sc) << 16);
    o.w = (unsigned)f2bf(b.z*sc) | ((unsigned)f2bf(b.w*sc) << 16);
    *((uint4*)dst + lane) = o;
}

// ---------------------------------------------------------------- histogram
__global__ __launch_bounds__(256) void hist_kernel(
    const int* __restrict__ labels, int* __restrict__ hist_g)
{
    __shared__ int hist[NLAB];
    int tid = threadIdx.x;
    if (tid < NLAB) hist[tid] = 0;
    __syncthreads();
    for (int i = tid; i < N_ROWS; i += 256) {
        int lb = labels[i];
        if (lb >= 0 && lb < NLAB) atomicAdd(&hist[lb], 1);
    }
    __syncthreads();
    if (tid < NLAB) hist_g[tid] = hist[tid];
}

// ---------------------------------------------------------------- class sums
// csum[dir][l][:] = sum of (dir? img : txt) rows whose label == l  (fp32)
__global__ __launch_bounds__(256) void classsum_kernel(
    const unsigned short* __restrict__ imgn, const unsigned short* __restrict__ txtn,
    const int* __restrict__ labels, float* __restrict__ csum)
{
    __shared__ float red[4][DIM];
    int dir = blockIdx.x >> 7;
    int l   = blockIdx.x & (NLAB - 1);
    const unsigned short* src = dir ? imgn : txtn;
    int w    = threadIdx.x >> 6;
    int lane = threadIdx.x & 63;
    float acc[8] = {0,0,0,0,0,0,0,0};
    int j0 = w * (N_ROWS / 4), j1 = j0 + N_ROWS / 4;
    for (int j = j0; j < j1; ++j) {
        if (labels[j] == l) {
            uint4 v = ((const uint4*)(src + (size_t)j * DIM))[lane];
            acc[0] += bflo(v.x); acc[1] += bfhi(v.x);
            acc[2] += bflo(v.y); acc[3] += bfhi(v.y);
            acc[4] += bflo(v.z); acc[5] += bfhi(v.z);
            acc[6] += bflo(v.w); acc[7] += bfhi(v.w);
        }
    }
    #pragma unroll
    for (int k = 0; k < 8; ++k) red[w][lane * 8 + k] = acc[k];
    __syncthreads();
    float* dst = csum + ((size_t)dir * NLAB + l) * DIM;
    #pragma unroll
    for (int it = 0; it < 2; ++it) {
        int d = it * 256 + threadIdx.x;
        dst[d] = red[0][d] + red[1][d] + red[2][d] + red[3][d];
    }
}

// ---------------------------------------------------------------- fused GEMM
#define ASYNC16(gp, lp) \
  __builtin_amdgcn_global_load_lds((const __attribute__((address_space(1))) void*)(gp), \
                                   (__attribute__((address_space(3))) void*)(lp), 16, 0, 0)

__global__ __launch_bounds__(256, 3) void gemm_fused_kernel(
    const unsigned short* __restrict__ imgn, const unsigned short* __restrict__ txtn,
    float* __restrict__ part)
{
    __shared__ unsigned short Ald[BM * 32];
    __shared__ unsigned short Bld[BN * 32];
    __shared__ float red[2][BM];

    int bid    = blockIdx.x;
    int dir    = bid >> 10;      // 0: rows=img, 1: rows=txt
    int rem    = bid & 1023;
    int rowblk = rem & 63;
    int chunk  = rem >> 6;       // 0..15
    const unsigned short* A = dir ? txtn : imgn;
    const unsigned short* B = dir ? imgn : txtn;
    int rowBase  = rowblk * BM;
    int colBase0 = chunk * CHUNK;

    int tid  = threadIdx.x;
    int lane = tid & 63;
    int w    = tid >> 6;
    int wr   = w >> 1, wc = w & 1;
    int q    = lane >> 4;
    int lm   = lane & 15;

    float s_acc[16];
    #pragma unroll
    for (int i = 0; i < 16; ++i) s_acc[i] = 0.f;

    // staging: lane L -> group-row L>>2, k-slot (L&3), XOR-swizzled global k-block
    int srow  = lane >> 2;
    int spart = (((lane & 3) ^ (srow & 3))) * 8;
    // read swizzle: k-block q of row rl lives at slot q ^ (rl&3) = q ^ (lm&3)
    int qx = ((q ^ (lm & 3))) * 8;

    const float C1 = SCALE * LOG2E;
    const float C2 = -MAXLOGIT * LOG2E;

    for (int tile = 0; tile < CHUNK / BN; ++tile) {
        int colBase = colBase0 + tile * BN;
        f32x4 acc[4][4];
        #pragma unroll
        for (int mi = 0; mi < 4; ++mi)
          #pragma unroll
          for (int ni = 0; ni < 4; ++ni)
            acc[mi][ni] = (f32x4){0.f, 0.f, 0.f, 0.f};

        for (int kt = 0; kt < DIM / 32; ++kt) {
            int k0 = kt * 32;
            __syncthreads();   // all waves done reading LDS before re-stage
            #pragma unroll
            for (int i = 0; i < 2; ++i) {
                int rlocal = i*64 + w*16 + srow;
                ASYNC16(A + (size_t)(rowBase + rlocal) * DIM + k0 + spart,
                        Ald + (i*64 + w*16) * 32);
                ASYNC16(B + (size_t)(colBase + rlocal) * DIM + k0 + spart,
                        Bld + (i*64 + w*16) * 32);
            }
            __syncthreads();   // drains vmcnt(0): staging complete

            short8 af[4], bf[4];
            #pragma unroll
            for (int mi = 0; mi < 4; ++mi)
                af[mi] = *(const short8*)(Ald + (wr*64 + mi*16 + lm)*32 + qx);
            #pragma unroll
            for (int ni = 0; ni < 4; ++ni)
                bf[ni] = *(const short8*)(Bld + (wc*64 + ni*16 + lm)*32 + qx);
            #pragma unroll
            for (int mi = 0; mi < 4; ++mi)
              #pragma unroll
              for (int ni = 0; ni < 4; ++ni)
                acc[mi][ni] = __builtin_amdgcn_mfma_f32_16x16x32_bf16(
                                  af[mi], bf[ni], acc[mi][ni], 0, 0, 0);
        }

        // epilogue: exp-sum only (fixed max 2.659); d handled via class sums
        #pragma unroll
        for (int ni = 0; ni < 4; ++ni)
          #pragma unroll
          for (int mi = 0; mi < 4; ++mi)
            #pragma unroll
            for (int r = 0; r < 4; ++r)
              s_acc[mi*4 + r] += __builtin_amdgcn_exp2f(
                                    __fmaf_rn(acc[mi][ni][r], C1, C2));
    }

    // reduce across the 16 column-lanes (low 4 lane bits)
    #pragma unroll
    for (int idx = 0; idx < 16; ++idx) {
        float s = s_acc[idx];
        #pragma unroll
        for (int m = 1; m < 16; m <<= 1) s += __shfl_xor(s, m, 64);
        s_acc[idx] = s;
    }
    if (lm == 0) {
        #pragma unroll
        for (int idx = 0; idx < 16; ++idx) {
            int rl = wr*64 + (idx>>2)*16 + q*4 + (idx&3);
            red[wc][rl] = s_acc[idx];
        }
    }
    __syncthreads();
    if (tid < BM)
        part[(size_t)(dir * NCHUNK + chunk) * N_ROWS + rowBase + tid]
            = red[0][tid] + red[1][tid];
}

// ---------------------------------------------------------------- loss stage 1
// one wave per (dir, i): dot(a_i, c_{lab_i}) (or a_i . b_i if lab<0) + lse merge
__global__ __launch_bounds__(256) void loss_stage1_kernel(
    const unsigned short* __restrict__ imgn, const unsigned short* __restrict__ txtn,
    const int* __restrict__ labels, const float* __restrict__ part,
    const float* __restrict__ csum, const int* __restrict__ hist,
    float* __restrict__ partial)
{
    __shared__ float wsum[4];
    int w    = threadIdx.x >> 6;
    int lane = threadIdx.x & 63;
    int wid  = blockIdx.x * 4 + w;
    int dir  = wid >> 13;
    int i    = wid & (N_ROWS - 1);
    int lab  = labels[i];

    const unsigned short* arow = (dir ? txtn : imgn) + (size_t)i * DIM;
    uint4 av = ((const uint4*)arow)[lane];
    float a0 = bflo(av.x), a1 = bfhi(av.x), a2 = bflo(av.y), a3 = bfhi(av.y);
    float a4 = bflo(av.z), a5 = bfhi(av.z), a6 = bflo(av.w), a7 = bfhi(av.w);

    float dot;
    if (lab < 0) {
        const unsigned short* brow = (dir ? imgn : txtn) + (size_t)i * DIM;
        uint4 bv = ((const uint4*)brow)[lane];
        dot = a0*bflo(bv.x) + a1*bfhi(bv.x) + a2*bflo(bv.y) + a3*bfhi(bv.y)
            + a4*bflo(bv.z) + a5*bfhi(bv.z) + a6*bflo(bv.w) + a7*bfhi(bv.w);
    } else {
        const float4* crow = (const float4*)(csum + ((size_t)dir * NLAB + lab) * DIM);
        float4 c0 = crow[lane * 2], c1 = crow[lane * 2 + 1];
        dot = a0*c0.x + a1*c0.y + a2*c0.z + a3*c0.w
            + a4*c1.x + a5*c1.y + a6*c1.z + a7*c1.w;
    }

    float s = (lane < NCHUNK)
            ? part[((size_t)dir * NCHUNK + lane) * N_ROWS + i] : 0.f;
    #pragma unroll
    for (int m = 1; m < 64; m <<= 1) {
        dot += __shfl_xor(dot, m, 64);
        s   += __shfl_xor(s,   m, 64);
    }
    if (lane == 0) {
        float sumT = (lab < 0) ? 1.0f : (float)hist[lab];
        wsum[w] = (MAXLOGIT + __logf(s)) - SCALE * dot / sumT;
    }
    __syncthreads();
    if (threadIdx.x == 0)
        partial[blockIdx.x] = wsum[0] + wsum[1] + wsum[2] + wsum[3];
}

// ---------------------------------------------------------------- loss stage 2
__global__ __launch_bounds__(256) void loss_stage2_kernel(
    const float* __restrict__ partial, float* __restrict__ out)
{
    __shared__ float ws[4];
    int tid = threadIdx.x, lane = tid & 63;
    float v = 0.f;
    for (int k = tid; k < 2 * N_ROWS / 4; k += 256) v += partial[k];
    #pragma unroll
    for (int m = 1; m < 64; m <<= 1) v += __shfl_xor(v, m, 64);
    if (lane == 0) ws[tid >> 6] = v;
    __syncthreads();
    if (tid == 0) out[0] = (ws[0] + ws[1] + ws[2] + ws[3]) * (1.0f / (2 * N_ROWS));
}

// ---------------------------------------------------------------- launch
extern "C" void kernel_launch(void* const* d_in, const int* in_sizes, int n_in,
                              void* d_out, int out_size, void* d_ws, size_t ws_size,
                              hipStream_t stream)
{
    const float* text   = (const float*)d_in[0];
    const float* image  = (const float*)d_in[1];
    const int*   labels = (const int*)d_in[2];

    unsigned short* imgn = (unsigned short*)d_ws;
    unsigned short* txtn = imgn + (size_t)N_ROWS * DIM;
    char* base = (char*)d_ws + 2 * (size_t)N_ROWS * DIM * sizeof(unsigned short);
    float* part    = (float*)base;                                   // 2*16*8192*4 = 1 MB
    float* csum    = part + 2 * NCHUNK * (size_t)N_ROWS;             // 2*128*512*4 = 256 KB
    int*   hist    = (int*)(csum + 2 * NLAB * DIM);                  // 512 B
    float* partial = (float*)(hist + NLAB);                          // 16 KB
    float* out     = (float*)d_out;

    hipLaunchKernelGGL(norm_cast_kernel, dim3(2 * N_ROWS / 4), dim3(256), 0, stream,
                       text, image, imgn, txtn);
    hipLaunchKernelGGL(hist_kernel, dim3(1), dim3(256), 0, stream, labels, hist);
    hipLaunchKernelGGL(classsum_kernel, dim3(2 * NLAB), dim3(256), 0, stream,
                       imgn, txtn, labels, csum);
    hipLaunchKernelGGL(gemm_fused_kernel, dim3(2 * 64 * NCHUNK), dim3(256), 0, stream,
                       imgn, txtn, part);
    hipLaunchKernelGGL(loss_stage1_kernel, dim3(2 * N_ROWS / 4), dim3(256), 0, stream,
                       imgn, txtn, labels, part, csum, hist, partial);
    hipLaunchKernelGGL(loss_stage2_kernel, dim3(1), dim3(256), 0, stream, partial, out);
}